// Round 1
// 1209.564 us; speedup vs baseline: 1.0473x; 1.0473x over previous
//
#include <hip/hip_runtime.h>

// R15: 1 sequence per wave (2048 waves = 2 waves/SIMD) instead of 2 seqs in
// 1 wave (1024 waves = 1 wave/SIMD). The R14 static de-interleave reached
// VALUBusy=62%; the residual 38% is trans-chain + LDS latency that a single
// wave cannot fill. Two co-resident waves fill it dynamically.
//
// Register economics (the reason R14 was stuck at 1 wave/SIMD): the SIMD
// register file is 512 wave-regs; R14 held 208 weight floats (AGPR) + 136
// VGPRs per wave. Here the G and O gate tables move to LDS, SHARED by the
// 4 waves of a block (one copy per block, 27.6 KB), leaving only I (with the
// z-row W_ih2 fold, which must stay per-lane exact) and F in registers:
// 104 weight regs + ~50 working regs -> 2 waves/SIMD fit.
//
// LDS weight layout: [2][64][54] f32, row stride 54 dwords (216 B). Lane j
// reads ds_read_b64 at unit offset 54*j + 2*kk: lanes collide only at
// dj=16 (4 lanes/bank-pair) == the conflict-free wave64 b64 baseline.
// Math is value- and order-identical to R14 -> absmax unchanged.

#define H1N  51
#define NP   26    // k-pairs: k=0..51; k=51 slot = bias (hrow[51]=1.0)
#define WAVE 64
#define WPB  4     // waves (= sequences) per block
#define WST  54    // LDS weight row stride in floats (27 pairs, 216 B)

typedef float v2f __attribute__((ext_vector_type(2)));

#define INV_LN2   1.44269504088896340736f
#define INV_LN2X2 2.88539008177792681472f

__device__ __forceinline__ float sigmoid_s(float xs) {   // input pre-scaled by 1/ln2
    return __builtin_amdgcn_rcpf(1.0f + __builtin_amdgcn_exp2f(-xs));
}
__device__ __forceinline__ float tanh_s2(float xs2) {    // input pre-scaled by 2/ln2
    float e = __builtin_amdgcn_exp2f(xs2);
    return fmaf(-2.0f, __builtin_amdgcn_rcpf(e + 1.0f), 1.0f);
}
__device__ __forceinline__ float tanh_nat(float x) {
    return tanh_s2(x * INV_LN2X2);
}
__device__ __forceinline__ float rdlane(float v, int k) {
    return __int_as_float(__builtin_amdgcn_readlane(__float_as_int(v), k));
}

__global__ __attribute__((amdgpu_flat_work_group_size(256, 256),
                          amdgpu_waves_per_eu(2)))
void lstm_seq1(const float* __restrict__ input,   // [B, T]
               const float* __restrict__ W_ih1,   // [204, 1]
               const float* __restrict__ W_hh1,   // [204, 51]
               const float* __restrict__ b_ih1,   // [204]
               const float* __restrict__ b_hh1,   // [204]
               const float* __restrict__ W_ih2,   // [4, 51]
               const float* __restrict__ W_hh2,   // [4, 1]
               const float* __restrict__ b_ih2,   // [4]
               const float* __restrict__ b_hh2,   // [4]
               float* __restrict__ out,           // [B, T+F]
               int T, int TF)
{
    const int tid = threadIdx.x;
    const int j   = tid & (WAVE - 1);
    const int wid = tid >> 6;
    const bool jv = (j < H1N);
    const int jj  = jv ? j : 0;
    const float m = jv ? 1.0f : 0.0f;
    const bool isz = (j >= H1N) && (j < H1N + 4);   // z-row lanes 51..54
    const int  q   = isz ? (j - H1N) : 0;
    const float mz = isz ? 1.0f : 0.0f;
    const float s2q = (q == 2) ? INV_LN2X2 : INV_LN2;  // LSTM2 gate scale

    const int s = blockIdx.x * WPB + wid;              // sequence index

    const int r_i = jj, r_f = H1N + jj, r_g = 2*H1N + jj, r_o = 3*H1N + jj;
    const float s_i = INV_LN2, s_f = INV_LN2, s_g = INV_LN2X2, s_o = INV_LN2;

    __shared__ __align__(16) float wlds[2][WAVE][WST]; // [G,O][lane][k] shared by 4 waves
    __shared__ __align__(16) float hrow[WPB][WAVE];
    __shared__ __align__(16) float zbs[WPB][4];

    // Register-resident weights: I (z-rows folded in) and F. Scaled; bias in
    // the k=51 slot (hrow[51]==1.0).
    v2f wI[NP], wF[NP];
#pragma unroll
    for (int kk = 0; kk < NP; ++kk) {
        const int k0 = 2*kk, k1 = k0 + 1;
        wI[kk].x = m*s_i*W_hh1[r_i*H1N + k0] + mz*s2q*W_ih2[q*H1N + k0];
        wF[kk].x = m*s_f*W_hh1[r_f*H1N + k0];
        if (k1 < H1N) {
            wI[kk].y = m*s_i*W_hh1[r_i*H1N + k1] + mz*s2q*W_ih2[q*H1N + k1];
            wF[kk].y = m*s_f*W_hh1[r_f*H1N + k1];
        } else {   // k1 == 51: bias slot; z-rows get 0
            wI[kk].y = m*s_i*(b_ih1[r_i] + b_hh1[r_i]);
            wF[kk].y = m*s_f*(b_ih1[r_f] + b_hh1[r_f]);
        }
    }
#pragma unroll
    for (int kk = 0; kk < NP; ++kk)
        asm volatile("" : "+v"(wI[kk]), "+v"(wF[kk]));   // pin: no remat from global

    // LDS-shared G/O weight tables (wave 0 fills; identical values for all waves).
    if (tid < WAVE) {
#pragma unroll
        for (int kk = 0; kk < NP; ++kk) {
            const int k0 = 2*kk, k1 = k0 + 1;
            const float g0 = m*s_g*W_hh1[r_g*H1N + k0];
            const float o0 = m*s_o*W_hh1[r_o*H1N + k0];
            float g1, o1;
            if (k1 < H1N) {
                g1 = m*s_g*W_hh1[r_g*H1N + k1];
                o1 = m*s_o*W_hh1[r_o*H1N + k1];
            } else {
                g1 = m*s_g*(b_ih1[r_g] + b_hh1[r_g]);
                o1 = m*s_o*(b_ih1[r_o] + b_hh1[r_o]);
            }
            wlds[0][j][k0] = g0; wlds[0][j][k0+1] = g1;
            wlds[1][j][k0] = o0; wlds[1][j][k0+1] = o1;
        }
    }

    const float wx_i = m*s_i*W_ih1[r_i];
    const float wx_f = m*s_f*W_ih1[r_f];
    const float wx_g = m*s_g*W_ih1[r_g];
    const float wx_o = m*s_o*W_ih1[r_o];

    // LSTM2 thread-uniform scalars, pre-scaled.
    const float wh2_0 = INV_LN2*W_hh2[0], wh2_1 = INV_LN2*W_hh2[1];
    const float wh2_2 = INV_LN2X2*W_hh2[2], wh2_3 = INV_LN2*W_hh2[3];
    const float b2_0 = INV_LN2*(b_ih2[0] + b_hh2[0]), b2_1 = INV_LN2*(b_ih2[1] + b_hh2[1]);
    const float b2_2 = INV_LN2X2*(b_ih2[2] + b_hh2[2]), b2_3 = INV_LN2*(b_ih2[3] + b_hh2[3]);

    hrow[wid][j] = (j == H1N) ? 1.0f : 0.0f;   // h1(-1)=0; [51]=1.0 (bias lane)
    __syncthreads();                            // weight tables ready; only sync

    float* __restrict__ hw  = hrow[wid];
    float* __restrict__ zbw = zbs[wid];
    const float* __restrict__ wgt = &wlds[0][j][0];
    const float* __restrict__ wot = &wlds[1][j][0];

    float c1 = 0.0f, h2 = 0.0f, c2 = 0.0f;

    const float* __restrict__ xrow = input + (long)s * T;
    float* __restrict__ orow = out + (long)s * TF;

    float xbuf = 0.0f, obuf = 0.0f;

    // One pipeline phase: matvec on h1(n-1) -> [LSTM2 step n-1] -> [finish
    // LSTM1 step n]. xmode/do_l2/do_fin are compile-time at each call site.
    auto phase = [&](float xin, int xmode, int do_l2, int do_fin, int tt) {
        v2f aI = {0.0f, 0.0f}, aF = {0.0f, 0.0f};
        v2f aG = {0.0f, 0.0f}, aO = {0.0f, 0.0f};
#pragma unroll
        for (int kk = 0; kk < NP; ++kk) {
            const v2f hp = *(const v2f*)&hw[2*kk];    // ds_read_b64 broadcast
            const v2f gk = *(const v2f*)&wgt[2*kk];   // per-lane, conflict-free
            const v2f ok = *(const v2f*)&wot[2*kk];
            asm("v_pk_fma_f32 %0, %4, %8, %0\n\t"
                "v_pk_fma_f32 %1, %5, %8, %1\n\t"
                "v_pk_fma_f32 %2, %6, %8, %2\n\t"
                "v_pk_fma_f32 %3, %7, %8, %3"
                : "+v"(aI), "+v"(aF), "+v"(aG), "+v"(aO)
                : "v"(wI[kk]), "v"(wF[kk]), "v"(gk), "v"(ok), "v"(hp));
        }
        const float mI = aI.x + aI.y;
        if (isz) zbw[q] = mI;                  // z_q(n-1) from the z-row lanes
        const float mF = aF.x + aF.y, mG = aG.x + aG.y, mO = aO.x + aO.y;

        if (do_l2) {                           // LSTM2 step n-1 (wave-uniform)
            const float4 z = *(const float4*)zbw;   // ds_read_b128 broadcast
            const float g2i = sigmoid_s(fmaf(wh2_0, h2, b2_0 + z.x));
            const float g2f = sigmoid_s(fmaf(wh2_1, h2, b2_1 + z.y));
            const float g2g = tanh_s2 (fmaf(wh2_2, h2, b2_2 + z.z));
            const float g2o = sigmoid_s(fmaf(wh2_3, h2, b2_3 + z.w));
            c2 = fmaf(g2f, c2, g2i * g2g);
            h2 = g2o * tanh_nat(c2);
            obuf = (j == (tt & 63)) ? h2 : obuf;    // predicated pack
        }
        if (do_fin) {                          // finish LSTM1 step n
            const float x = (xmode == 0) ? xin : h2;
            const float gi = sigmoid_s(fmaf(wx_i, x, mI));
            const float gf = sigmoid_s(fmaf(wx_f, x, mF));
            const float gg = tanh_s2 (fmaf(wx_g, x, mG));
            const float go = sigmoid_s(fmaf(wx_o, x, mO));
            c1 = fmaf(gf, c1, gi * gg);
            const float h1 = go * tanh_nat(c1);
            if (jv) hw[j] = h1;                // publish h1(n)
        }
    };

    // ---- Prologue: iteration n=0 (no LSTM2 yet) ----
    xbuf = xrow[j];
    phase(rdlane(xbuf, 0), 0, 0, 1, 0);

    // ---- Warm loop: n = 1..T-1 (x from input) ----
    for (int n = 1; n < T; ++n) {
        if ((n & 63) == 0) xbuf = xrow[n + j];
        const float x = rdlane(xbuf, n & 63);
        phase(x, 0, 1, 1, n - 1);
        if ((n & 63) == 0) orow[n - 64 + j] = obuf;   // flush tt = n-64..n-1
    }

    // ---- Boundary: n = T (LSTM2 for T-1; first feedback step x=h2) ----
    phase(0.0f, 1, 1, 1, T - 1);
    orow[T - 64 + j] = obuf;                  // flush tt = T-64..T-1

    // ---- Future loop: n = T+1..TF-1 (x = h2 feedback) ----
    for (int n = T + 1; n < TF; ++n)
        phase(0.0f, 1, 1, 1, n - 1);

    // ---- Drain: n = TF (LSTM2 for TF-1 only) ----
    phase(0.0f, 1, 1, 0, TF - 1);
    orow[TF - 64 + j] = obuf;                 // flush tt = TF-64..TF-1
}

extern "C" void kernel_launch(void* const* d_in, const int* in_sizes, int n_in,
                              void* d_out, int out_size, void* d_ws, size_t ws_size,
                              hipStream_t stream) {
    const float* input = (const float*)d_in[0];
    const float* W_ih1 = (const float*)d_in[1];
    const float* W_hh1 = (const float*)d_in[2];
    const float* b_ih1 = (const float*)d_in[3];
    const float* b_hh1 = (const float*)d_in[4];
    const float* W_ih2 = (const float*)d_in[5];
    const float* W_hh2 = (const float*)d_in[6];
    const float* b_ih2 = (const float*)d_in[7];
    const float* b_hh2 = (const float*)d_in[8];
    float* out = (float*)d_out;

    const int B  = 2048;
    const int T  = in_sizes[0] / B;      // 1024
    const int TF = out_size   / B;       // 1088

    lstm_seq1<<<dim3(B / WPB), dim3(WPB * WAVE), 0, stream>>>(
        input, W_ih1, W_hh1, b_ih1, b_hh1, W_ih2, W_hh2, b_ih2, b_hh2,
        out, T, TF);
}

// Round 2
// 1057.992 us; speedup vs baseline: 1.1973x; 1.1433x over previous
//
#include <hip/hip_runtime.h>

// R16: R14's register-resident weights + R15's 2 waves/SIMD, combined.
//
// R15 post-mortem: moving G/O weight tables to LDS bought occupancy
// (2 waves/SIMD) but saturated the per-CU LDS pipe: 8 waves/CU x 78 ds ops
// per phase x ~5 cyc ~= 3100 cyc/CU/step == the measured step time. VALUBusy
// stayed 61% -- the second wave's issue slots were eaten by lgkmcnt waits on
// a saturated LDS pipe, not by VALU work.
//
// Fix: 1 sequence/wave keeps the working set at ~25 regs (R15 measured
// VGPR=128 with 104 weight regs), so ALL 208 weight regs + working fit in
// 256 = 512/2 -> two waves/SIMD co-reside with amdgpu_waves_per_eu(2)
// capping the allocator. LDS per phase drops to ~16 ops (13 b128 hrow
// broadcasts + z exchange + h1 publish): ~650 cyc/CU/step, far under the
// ~1740 cyc/SIMD/step VALU issue budget. The sibling wave hides the serial
// activation tail dynamically.
//
// Facts carried forward:
//  - VOP3P cannot read AGPRs on gfx950; if the RA parks overflow weights in
//    AGPRs it inserts read-shuttles (acceptable; R14 proved this works).
//  - v_pk_fma_f32 has no rate advantage over scalar f32; kept to halve
//    instruction count.
//  - hrow reads as ds_read_b128 broadcasts (4 floats), halving broadcast
//    instruction count vs b64.
// Math is value- and order-identical to R14/R15 -> absmax unchanged.

#define H1N  51
#define NP   26    // k-pairs: k=0..51; k=51 slot = bias (hrow[51]=1.0)
#define NQ   13    // k-quads for the b128 hrow broadcast reads
#define WAVE 64

typedef float v2f __attribute__((ext_vector_type(2)));
typedef float v4f __attribute__((ext_vector_type(4)));

#define INV_LN2   1.44269504088896340736f
#define INV_LN2X2 2.88539008177792681472f

__device__ __forceinline__ float sigmoid_s(float xs) {   // input pre-scaled by 1/ln2
    return __builtin_amdgcn_rcpf(1.0f + __builtin_amdgcn_exp2f(-xs));
}
__device__ __forceinline__ float tanh_s2(float xs2) {    // input pre-scaled by 2/ln2
    float e = __builtin_amdgcn_exp2f(xs2);
    return fmaf(-2.0f, __builtin_amdgcn_rcpf(e + 1.0f), 1.0f);
}
__device__ __forceinline__ float tanh_nat(float x) {
    return tanh_s2(x * INV_LN2X2);
}
__device__ __forceinline__ float rdlane(float v, int k) {
    return __int_as_float(__builtin_amdgcn_readlane(__float_as_int(v), k));
}

__global__ __attribute__((amdgpu_flat_work_group_size(64, 64),
                          amdgpu_waves_per_eu(2)))
void lstm_seq1r(const float* __restrict__ input,   // [B, T]
                const float* __restrict__ W_ih1,   // [204, 1]
                const float* __restrict__ W_hh1,   // [204, 51]
                const float* __restrict__ b_ih1,   // [204]
                const float* __restrict__ b_hh1,   // [204]
                const float* __restrict__ W_ih2,   // [4, 51]
                const float* __restrict__ W_hh2,   // [4, 1]
                const float* __restrict__ b_ih2,   // [4]
                const float* __restrict__ b_hh2,   // [4]
                float* __restrict__ out,           // [B, T+F]
                int T, int TF)
{
    const int j   = threadIdx.x;
    const bool jv = (j < H1N);
    const int jj  = jv ? j : 0;
    const float m = jv ? 1.0f : 0.0f;
    const bool isz = (j >= H1N) && (j < H1N + 4);   // z-row lanes 51..54
    const int  q   = isz ? (j - H1N) : 0;
    const float mz = isz ? 1.0f : 0.0f;
    const float s2q = (q == 2) ? INV_LN2X2 : INV_LN2;  // LSTM2 gate scale

    const int s = blockIdx.x;                          // one sequence per wave

    const int r_i = jj, r_f = H1N + jj, r_g = 2*H1N + jj, r_o = 3*H1N + jj;
    const float s_i = INV_LN2, s_f = INV_LN2, s_g = INV_LN2X2, s_o = INV_LN2;

    __shared__ __align__(16) float hrow[WAVE];
    __shared__ __align__(16) float zb[4];

    // All four gate weight tables in registers (208 regs). Lanes<51 = the 4
    // gate rows of unit j (scaled; bias folded into the k=51 slot since
    // hrow[51]==1.0); lanes 51..54 carry W_ih2 row q in the gate-i slot.
    v2f wI[NP], wF[NP], wG[NP], wO[NP];
#pragma unroll
    for (int kk = 0; kk < NP; ++kk) {
        const int k0 = 2*kk, k1 = k0 + 1;
        wI[kk].x = m*s_i*W_hh1[r_i*H1N + k0] + mz*s2q*W_ih2[q*H1N + k0];
        wF[kk].x = m*s_f*W_hh1[r_f*H1N + k0];
        wG[kk].x = m*s_g*W_hh1[r_g*H1N + k0];
        wO[kk].x = m*s_o*W_hh1[r_o*H1N + k0];
        if (k1 < H1N) {
            wI[kk].y = m*s_i*W_hh1[r_i*H1N + k1] + mz*s2q*W_ih2[q*H1N + k1];
            wF[kk].y = m*s_f*W_hh1[r_f*H1N + k1];
            wG[kk].y = m*s_g*W_hh1[r_g*H1N + k1];
            wO[kk].y = m*s_o*W_hh1[r_o*H1N + k1];
        } else {   // k1 == 51: bias slot (hrow[51] == 1.0); z-rows get 0
            wI[kk].y = m*s_i*(b_ih1[r_i] + b_hh1[r_i]);
            wF[kk].y = m*s_f*(b_ih1[r_f] + b_hh1[r_f]);
            wG[kk].y = m*s_g*(b_ih1[r_g] + b_hh1[r_g]);
            wO[kk].y = m*s_o*(b_ih1[r_o] + b_hh1[r_o]);
        }
    }
    // One-time pin: anchors the masked-scaled weights as computed (blocks
    // remat-from-global), without in-loop round-trips.
#pragma unroll
    for (int kk = 0; kk < NP; ++kk)
        asm volatile("" : "+v"(wI[kk]), "+v"(wF[kk]), "+v"(wG[kk]), "+v"(wO[kk]));

    const float wx_i = m*s_i*W_ih1[r_i];
    const float wx_f = m*s_f*W_ih1[r_f];
    const float wx_g = m*s_g*W_ih1[r_g];
    const float wx_o = m*s_o*W_ih1[r_o];

    // LSTM2 thread-uniform scalars (SGPRs), pre-scaled.
    const float wh2_0 = INV_LN2*W_hh2[0], wh2_1 = INV_LN2*W_hh2[1];
    const float wh2_2 = INV_LN2X2*W_hh2[2], wh2_3 = INV_LN2*W_hh2[3];
    const float b2_0 = INV_LN2*(b_ih2[0] + b_hh2[0]), b2_1 = INV_LN2*(b_ih2[1] + b_hh2[1]);
    const float b2_2 = INV_LN2X2*(b_ih2[2] + b_hh2[2]), b2_3 = INV_LN2*(b_ih2[3] + b_hh2[3]);

    hrow[j] = (j == H1N) ? 1.0f : 0.0f;   // h1(-1)=0; [51]=1.0 (bias lane)

    float c1 = 0.0f, h2 = 0.0f, c2 = 0.0f;

    const float* __restrict__ xrow = input + (long)s * T;
    float* __restrict__ orow = out + (long)s * TF;

    float xbuf = 0.0f, obuf = 0.0f;

    // One pipeline phase: matvec on h1(n-1) -> [LSTM2 step n-1] -> [finish
    // LSTM1 step n]. xmode/do_l2/do_fin are compile-time at each call site.
    auto phase = [&](float xin, int xmode, int do_l2, int do_fin, int tt) {
        v2f aI = {0.0f, 0.0f}, aF = {0.0f, 0.0f};
        v2f aG = {0.0f, 0.0f}, aO = {0.0f, 0.0f};
#pragma unroll
        for (int kq = 0; kq < NQ; ++kq) {
            const v4f h4 = *(const v4f*)&hrow[4*kq];   // ds_read_b128 bcast
            const v2f hp0 = __builtin_shufflevector(h4, h4, 0, 1);
            const v2f hp1 = __builtin_shufflevector(h4, h4, 2, 3);
            asm("v_pk_fma_f32 %0, %4, %8, %0\n\t"
                "v_pk_fma_f32 %1, %5, %8, %1\n\t"
                "v_pk_fma_f32 %2, %6, %8, %2\n\t"
                "v_pk_fma_f32 %3, %7, %8, %3"
                : "+v"(aI), "+v"(aF), "+v"(aG), "+v"(aO)
                : "v"(wI[2*kq]), "v"(wF[2*kq]), "v"(wG[2*kq]), "v"(wO[2*kq]),
                  "v"(hp0));
            asm("v_pk_fma_f32 %0, %4, %8, %0\n\t"
                "v_pk_fma_f32 %1, %5, %8, %1\n\t"
                "v_pk_fma_f32 %2, %6, %8, %2\n\t"
                "v_pk_fma_f32 %3, %7, %8, %3"
                : "+v"(aI), "+v"(aF), "+v"(aG), "+v"(aO)
                : "v"(wI[2*kq+1]), "v"(wF[2*kq+1]), "v"(wG[2*kq+1]), "v"(wO[2*kq+1]),
                  "v"(hp1));
        }
        const float mI = aI.x + aI.y;
        if (isz) zb[q] = mI;                  // z_q(n-1) from the z-row lanes
        const float mF = aF.x + aF.y, mG = aG.x + aG.y, mO = aO.x + aO.y;

        if (do_l2) {                          // LSTM2 step n-1 (wave-uniform)
            const float4 z = *(const float4*)zb;   // ds_read_b128 bcast
            const float g2i = sigmoid_s(fmaf(wh2_0, h2, b2_0 + z.x));
            const float g2f = sigmoid_s(fmaf(wh2_1, h2, b2_1 + z.y));
            const float g2g = tanh_s2 (fmaf(wh2_2, h2, b2_2 + z.z));
            const float g2o = sigmoid_s(fmaf(wh2_3, h2, b2_3 + z.w));
            c2 = fmaf(g2f, c2, g2i * g2g);
            h2 = g2o * tanh_nat(c2);
            obuf = (j == (tt & 63)) ? h2 : obuf;   // predicated pack
        }
        if (do_fin) {                         // finish LSTM1 step n
            const float x = (xmode == 0) ? xin : h2;
            const float gi = sigmoid_s(fmaf(wx_i, x, mI));
            const float gf = sigmoid_s(fmaf(wx_f, x, mF));
            const float gg = tanh_s2 (fmaf(wx_g, x, mG));
            const float go = sigmoid_s(fmaf(wx_o, x, mO));
            c1 = fmaf(gf, c1, gi * gg);
            const float h1 = go * tanh_nat(c1);
            if (jv) hrow[j] = h1;             // publish h1(n)
        }
    };

    // ---- Prologue: iteration n=0 (no LSTM2 yet) ----
    xbuf = xrow[j];
    phase(rdlane(xbuf, 0), 0, 0, 1, 0);

    // ---- Warm loop: n = 1..T-1 (x from input) ----
    for (int n = 1; n < T; ++n) {
        if ((n & 63) == 0) xbuf = xrow[n + j];
        const float x = rdlane(xbuf, n & 63);
        phase(x, 0, 1, 1, n - 1);
        if ((n & 63) == 0) orow[n - 64 + j] = obuf;   // flush tt = n-64..n-1
    }

    // ---- Boundary: n = T (LSTM2 for T-1; first feedback step x=h2) ----
    phase(0.0f, 1, 1, 1, T - 1);
    orow[T - 64 + j] = obuf;                  // flush tt = T-64..T-1

    // ---- Future loop: n = T+1..TF-1 (x = h2 feedback) ----
    for (int n = T + 1; n < TF; ++n)
        phase(0.0f, 1, 1, 1, n - 1);

    // ---- Drain: n = TF (LSTM2 for TF-1 only) ----
    phase(0.0f, 1, 1, 0, TF - 1);
    orow[TF - 64 + j] = obuf;                 // flush tt = TF-64..TF-1
}

extern "C" void kernel_launch(void* const* d_in, const int* in_sizes, int n_in,
                              void* d_out, int out_size, void* d_ws, size_t ws_size,
                              hipStream_t stream) {
    const float* input = (const float*)d_in[0];
    const float* W_ih1 = (const float*)d_in[1];
    const float* W_hh1 = (const float*)d_in[2];
    const float* b_ih1 = (const float*)d_in[3];
    const float* b_hh1 = (const float*)d_in[4];
    const float* W_ih2 = (const float*)d_in[5];
    const float* W_hh2 = (const float*)d_in[6];
    const float* b_ih2 = (const float*)d_in[7];
    const float* b_hh2 = (const float*)d_in[8];
    float* out = (float*)d_out;

    const int B  = 2048;
    const int T  = in_sizes[0] / B;      // 1024
    const int TF = out_size   / B;       // 1088

    lstm_seq1r<<<dim3(B), dim3(WAVE), 0, stream>>>(
        input, W_ih1, W_hh1, b_ih1, b_hh1, W_ih2, W_hh2, b_ih2, b_hh2,
        out, T, TF);
}